// Round 4
// baseline (98.679 us; speedup 1.0000x reference)
//
#include <hip/hip_runtime.h>

// Chamfer, B=4, N=M=8192 fp32 -> scalar. Round 7: drop the LDS staging entirely.
// Round-6 post-mortem: mfma kernel ~36.5 us ~= SUM of pipe times (MFMA 16.6 + VALU 13.7
// + DS 10.2) -- pipes not overlapping under the 2-phase stage/vmcnt/barrier structure.
// B working set per block is 128 KB (L2-resident per XCD; 4 co-resident blocks share the
// same col window -> L1 catches re-reads), so LDS staging is pure overhead (guide
// common-mistake #7). Each lane now loads its B-fragment straight from tArr (16 B
// coalesced, same mapping the LDS slot held: pt=l15, qr=l4 -> identical arithmetic).
// No __shared__, no barriers, no vmcnt drains: waves are independent greedy streams;
// compiler vmcnt-counted prefetch replaces the barrier pipeline.

#define BATCH 4
#define NPTS 8192
#define SETPTS (BATCH * NPTS)       // 32768
#define TOTPTS (2 * SETPTS)         // 65536
#define NSLOT 32                    // bf16 K-slots per point (30 used)
#define CSPLIT 4                    // col-splits per (dirb, rowblock)
#define COLS_PER (NPTS / CSPLIT)    // 2048 cols per block
#define CT_PER (COLS_PER / 16)      // 128 col-tiles per block

typedef __attribute__((ext_vector_type(8))) short bf16x8;
typedef __attribute__((ext_vector_type(4))) float f32x4;

__device__ __forceinline__ float bf16rn(float v) {  // round-to-nearest-even to bf16 value
  unsigned u = __float_as_uint(v);
  u = (u + 0x7FFFu + ((u >> 16) & 1u)) & 0xFFFF0000u;
  return __uint_as_float(u);
}
__device__ __forceinline__ unsigned short b2u(float v) {  // bf16 bits of a bf16-valued f32
  return (unsigned short)(__float_as_uint(v) >> 16);
}

// Per point: s-vec (row role, carries the -2 factor) and t-vec (col role):
//   coord d: s[8d+]: [-2a,-2a,-2a,-2b,-2b,-2b,-2c,-2c]   t[8d+]: [d,e,f,d,e,f,d,e]
//     -> limb pairs ad,ae,af,bd,be,bf,cd,ce (drops only ~2^-36 c*f)
//   slots 24-26: s = split(|p|^2), t = 1 ; slots 27-29: s = 1, t = split(|q|^2); 30-31: 0.
__global__ __launch_bounds__(256) void chamfer_prep_kernel(
    const float* __restrict__ p1, const float* __restrict__ p2,
    unsigned short* __restrict__ sArr, unsigned short* __restrict__ tArr,
    unsigned int* __restrict__ wmin, float* __restrict__ out) {
  const int i = blockIdx.x * 256 + threadIdx.x;  // 0..65535
  const float* src = (i < SETPTS) ? (p1 + 3 * (size_t)i) : (p2 + 3 * (size_t)(i - SETPTS));
  const float co[3] = {src[0], src[1], src[2]};
  union { unsigned short u[32]; uint4 v[4]; } sv, tv;
#pragma unroll
  for (int d = 0; d < 3; ++d) {
    const float v = co[d];
    const float a = bf16rn(v), r1 = v - a;        // Sterbenz-exact residuals
    const float bb = bf16rn(r1), r2 = r1 - bb;
    const float cc = bf16rn(r2);
    const unsigned short as = b2u(-2.f * a), bs = b2u(-2.f * bb), cs2 = b2u(-2.f * cc);
    const unsigned short at = b2u(a), bt = b2u(bb), ct = b2u(cc);
    sv.u[8 * d + 0] = as; sv.u[8 * d + 1] = as; sv.u[8 * d + 2] = as;
    sv.u[8 * d + 3] = bs; sv.u[8 * d + 4] = bs; sv.u[8 * d + 5] = bs;
    sv.u[8 * d + 6] = cs2; sv.u[8 * d + 7] = cs2;
    tv.u[8 * d + 0] = at; tv.u[8 * d + 1] = bt; tv.u[8 * d + 2] = ct;
    tv.u[8 * d + 3] = at; tv.u[8 * d + 4] = bt; tv.u[8 * d + 5] = ct;
    tv.u[8 * d + 6] = at; tv.u[8 * d + 7] = bt;
  }
  const float sp = fmaf(co[0], co[0], fmaf(co[1], co[1], co[2] * co[2]));
  const float g = bf16rn(sp), q1 = sp - g;
  const float h = bf16rn(q1), q2 = q1 - h;
  const float ii = bf16rn(q2);
  sv.u[24] = b2u(g); sv.u[25] = b2u(h); sv.u[26] = b2u(ii);
  tv.u[24] = 0x3F80; tv.u[25] = 0x3F80; tv.u[26] = 0x3F80;  // bf16(1.0)
  sv.u[27] = 0x3F80; sv.u[28] = 0x3F80; sv.u[29] = 0x3F80;
  tv.u[27] = b2u(g); tv.u[28] = b2u(h); tv.u[29] = b2u(ii);
  sv.u[30] = 0; sv.u[31] = 0; tv.u[30] = 0; tv.u[31] = 0;
  uint4* sd = (uint4*)(sArr + (size_t)i * NSLOT);
  uint4* td = (uint4*)(tArr + (size_t)i * NSLOT);
#pragma unroll
  for (int k = 0; k < 4; ++k) { sd[k] = sv.v[k]; td[k] = tv.v[k]; }
  wmin[i] = 0x7F800000u;  // +inf bits: > any clamped finite float's bits
  if (i == 0) out[0] = 0.f;
}

// Block: 4 waves x 4 row-tiles = 256 rows, streams its 2048-col split (128 col-tiles).
// B-fragment for col-tile ct: lane reads 16 B at (csp*2048 + ct*16 + l15)*64 + l4*16 --
// the wave covers exactly 1 KB contiguously (perfect coalescing), L1/L2-resident.
__global__ __launch_bounds__(256, 4) void chamfer_mfma_kernel(
    const unsigned short* __restrict__ sArr, const unsigned short* __restrict__ tArr,
    unsigned int* __restrict__ wmin) {
  const int bx = blockIdx.x;
  const int dirb = bx & 7;         // bx%8 -> XCD-aligned: per-XCD L2 sees one dirb's t-set
  const int rblk = (bx >> 3) & 31; // 0..31 (256 rows each)
  const int csp = bx >> 8;         // 0..3 (2048 cols each)
  const int dir = dirb >> 2, b = dirb & 3;
  const unsigned short* sb = sArr + (size_t)((dir ? SETPTS : 0) + b * NPTS) * NSLOT;
  const unsigned short* tb = tArr + (size_t)((dir ? 0 : SETPTS) + b * NPTS) * NSLOT;
  unsigned int* wm = wmin + (size_t)dirb * NPTS;

  const int t = threadIdx.x;
  const int lane = t & 63, wid = t >> 6;
  const int l15 = lane & 15, l4 = lane >> 4;

  const int rowbase = rblk * 256 + wid * 64;   // wave owns 64 rows = 4 row-tiles
  bf16x8 a0, a1, a2, a3;
  a0 = *(const bf16x8*)(sb + (size_t)(rowbase + 0 * 16 + l15) * NSLOT + l4 * 8);
  a1 = *(const bf16x8*)(sb + (size_t)(rowbase + 1 * 16 + l15) * NSLOT + l4 * 8);
  a2 = *(const bf16x8*)(sb + (size_t)(rowbase + 2 * 16 + l15) * NSLOT + l4 * 8);
  a3 = *(const bf16x8*)(sb + (size_t)(rowbase + 3 * 16 + l15) * NSLOT + l4 * 8);

  // per-lane B base: this lane's (col, k-quarter) slot within the col-split
  const unsigned short* tq = tb + (size_t)(csp * COLS_PER + l15) * NSLOT + l4 * 8;

  f32x4 acc0 = {INFINITY, INFINITY, INFINITY, INFINITY};
  f32x4 acc1 = acc0, acc2 = acc0, acc3 = acc0;
  const f32x4 zero = {0.f, 0.f, 0.f, 0.f};

#pragma unroll 8
  for (int ct = 0; ct < CT_PER; ct += 2) {  // col-tile PAIRS: min3 folds two results/op
    const bf16x8 bfA = *(const bf16x8*)(tq + (size_t)ct * (16 * NSLOT));
    const bf16x8 bfB = *(const bf16x8*)(tq + (size_t)(ct + 1) * (16 * NSLOT));
    const f32x4 dA0 = __builtin_amdgcn_mfma_f32_16x16x32_bf16(a0, bfA, zero, 0, 0, 0);
    const f32x4 dB0 = __builtin_amdgcn_mfma_f32_16x16x32_bf16(a0, bfB, zero, 0, 0, 0);
    const f32x4 dA1 = __builtin_amdgcn_mfma_f32_16x16x32_bf16(a1, bfA, zero, 0, 0, 0);
    const f32x4 dB1 = __builtin_amdgcn_mfma_f32_16x16x32_bf16(a1, bfB, zero, 0, 0, 0);
    const f32x4 dA2 = __builtin_amdgcn_mfma_f32_16x16x32_bf16(a2, bfA, zero, 0, 0, 0);
    const f32x4 dB2 = __builtin_amdgcn_mfma_f32_16x16x32_bf16(a2, bfB, zero, 0, 0, 0);
    const f32x4 dA3 = __builtin_amdgcn_mfma_f32_16x16x32_bf16(a3, bfA, zero, 0, 0, 0);
    const f32x4 dB3 = __builtin_amdgcn_mfma_f32_16x16x32_bf16(a3, bfB, zero, 0, 0, 0);
#pragma unroll
    for (int r = 0; r < 4; ++r) {
      acc0[r] = fminf(fminf(acc0[r], dA0[r]), dB0[r]);  // v_min3_f32
      acc1[r] = fminf(fminf(acc1[r], dA1[r]), dB1[r]);
      acc2[r] = fminf(fminf(acc2[r], dA2[r]), dB2[r]);
      acc3[r] = fminf(fminf(acc3[r], dA3[r]), dB3[r]);
    }
  }

  // fold the 16 col-lanes (same lane>>4 group) -> this block's row-mins
#pragma unroll
  for (int m = 1; m <= 8; m <<= 1) {
#pragma unroll
    for (int r = 0; r < 4; ++r) {
      acc0[r] = fminf(acc0[r], __shfl_xor(acc0[r], m, 64));
      acc1[r] = fminf(acc1[r], __shfl_xor(acc1[r], m, 64));
      acc2[r] = fminf(acc2[r], __shfl_xor(acc2[r], m, 64));
      acc3[r] = fminf(acc3[r], __shfl_xor(acc3[r], m, 64));
    }
  }
  if (l15 == 0) {  // C/D: col=lane&15, row=(lane>>4)*4+r [m89]
#pragma unroll
    for (int r = 0; r < 4; ++r) {
      atomicMin(&wm[rowbase + 0 * 16 + l4 * 4 + r], __float_as_uint(fmaxf(acc0[r], 0.f)));
      atomicMin(&wm[rowbase + 1 * 16 + l4 * 4 + r], __float_as_uint(fmaxf(acc1[r], 0.f)));
      atomicMin(&wm[rowbase + 2 * 16 + l4 * 4 + r], __float_as_uint(fmaxf(acc2[r], 0.f)));
      atomicMin(&wm[rowbase + 3 * 16 + l4 * 4 + r], __float_as_uint(fmaxf(acc3[r], 0.f)));
    }
  }
}

__global__ __launch_bounds__(256) void chamfer_reduce_kernel(const unsigned int* __restrict__ wmin,
                                                             float* __restrict__ out) {
  // 65536 elements; 64 blocks x 256 threads x 4 elems
  float s = 0.f;
  const int base = blockIdx.x * 1024 + threadIdx.x;
#pragma unroll
  for (int k = 0; k < 4; ++k) s += __uint_as_float(wmin[base + k * 256]);
#pragma unroll
  for (int off = 32; off > 0; off >>= 1) s += __shfl_down(s, off, 64);
  __shared__ float wsum[4];
  const int lane = threadIdx.x & 63, wid = threadIdx.x >> 6;
  if (lane == 0) wsum[wid] = s;
  __syncthreads();
  if (threadIdx.x == 0) atomicAdd(out, wsum[0] + wsum[1] + wsum[2] + wsum[3]);
}

extern "C" void kernel_launch(void* const* d_in, const int* in_sizes, int n_in,
                              void* d_out, int out_size, void* d_ws, size_t ws_size,
                              hipStream_t stream) {
  const float* p1 = (const float*)d_in[0];
  const float* p2 = (const float*)d_in[1];
  float* out = (float*)d_out;
  unsigned short* sArr = (unsigned short*)d_ws;                       // 4 MB
  unsigned short* tArr = (unsigned short*)((char*)d_ws + (4 << 20));  // 4 MB
  unsigned int* wmin = (unsigned int*)((char*)d_ws + (8 << 20));      // 256 KB

  chamfer_prep_kernel<<<dim3(TOTPTS / 256), dim3(256), 0, stream>>>(p1, p2, sArr, tArr, wmin, out);
  chamfer_mfma_kernel<<<dim3(8 * 32 * CSPLIT), dim3(256), 0, stream>>>(sArr, tArr, wmin);
  chamfer_reduce_kernel<<<dim3(64), dim3(256), 0, stream>>>(wmin, out);
}

// Round 5
// 94.306 us; speedup vs baseline: 1.0464x; 1.0464x over previous
//
#include <hip/hip_runtime.h>

// Chamfer, B=4, N=M=8192 fp32 -> scalar. Round 8: 8 row-tiles/wave.
// Round-7 post-mortem: dropping LDS HURT (+5.4 us) -- VMEM latency at 4 waves/SIMD is
// worse than the staging overhead; round-6 LDS structure restored. Corrected pipe model:
// MFMA floor 16.6 us @2.4GHz (~25 us at sustained mixed-load clock); round 6 ran 36.4 us
// = ~45% MFMA util. Fix: double A-reuse -- each wave owns 8 row-tiles (128 rows), so one
// ds_read_b128 B-fragment feeds 8 MFMAs (was 4). Per-pair-iteration: 2 ds_read + 16 MFMA
// (310 SIMD-cyc) + 32 min3 (64 cyc) -> 4.4:1 MFMA:other. Block = 512 rows x 1024 cols
// (CSPLIT=8), grid 1024 = 4 blocks/CU, 32KB LDS, 4 chunks -> 4 barriers/block.

#define BATCH 4
#define NPTS 8192
#define SETPTS (BATCH * NPTS)       // 32768
#define TOTPTS (2 * SETPTS)         // 65536
#define NSLOT 32                    // bf16 K-slots per point (30 used)
#define CHUNK_PTS 256               // col points staged per chunk = 16 tiles
#define CSPLIT 8                    // col-splits per (dirb, rowblock)
#define COLS_PER (NPTS / CSPLIT)    // 1024 cols per block
#define CHUNKS_PER (COLS_PER / CHUNK_PTS)        // 4 chunks per block
#define CHUNK_BYTES (CHUNK_PTS * NSLOT * 2)      // 16384
#define RT 8                        // row-tiles per wave
#define ROWS_BLK (4 * RT * 16)      // 512 rows per block
#define RBLK (NPTS / ROWS_BLK)      // 16 row-blocks

typedef __attribute__((ext_vector_type(8))) short bf16x8;
typedef __attribute__((ext_vector_type(4))) float f32x4;

__device__ __forceinline__ float bf16rn(float v) {  // round-to-nearest-even to bf16 value
  unsigned u = __float_as_uint(v);
  u = (u + 0x7FFFu + ((u >> 16) & 1u)) & 0xFFFF0000u;
  return __uint_as_float(u);
}
__device__ __forceinline__ unsigned short b2u(float v) {  // bf16 bits of a bf16-valued f32
  return (unsigned short)(__float_as_uint(v) >> 16);
}

// Per point: s-vec (row role, carries the -2 factor) and t-vec (col role):
//   coord d: s[8d+]: [-2a,-2a,-2a,-2b,-2b,-2b,-2c,-2c]   t[8d+]: [d,e,f,d,e,f,d,e]
//     -> limb pairs ad,ae,af,bd,be,bf,cd,ce (drops only ~2^-36 c*f)
//   slots 24-26: s = split(|p|^2), t = 1 ; slots 27-29: s = 1, t = split(|q|^2); 30-31: 0.
__global__ __launch_bounds__(256) void chamfer_prep_kernel(
    const float* __restrict__ p1, const float* __restrict__ p2,
    unsigned short* __restrict__ sArr, unsigned short* __restrict__ tArr,
    unsigned int* __restrict__ wmin, float* __restrict__ out) {
  const int i = blockIdx.x * 256 + threadIdx.x;  // 0..65535
  const float* src = (i < SETPTS) ? (p1 + 3 * (size_t)i) : (p2 + 3 * (size_t)(i - SETPTS));
  const float co[3] = {src[0], src[1], src[2]};
  union { unsigned short u[32]; uint4 v[4]; } sv, tv;
#pragma unroll
  for (int d = 0; d < 3; ++d) {
    const float v = co[d];
    const float a = bf16rn(v), r1 = v - a;        // Sterbenz-exact residuals
    const float bb = bf16rn(r1), r2 = r1 - bb;
    const float cc = bf16rn(r2);
    const unsigned short as = b2u(-2.f * a), bs = b2u(-2.f * bb), cs2 = b2u(-2.f * cc);
    const unsigned short at = b2u(a), bt = b2u(bb), ct = b2u(cc);
    sv.u[8 * d + 0] = as; sv.u[8 * d + 1] = as; sv.u[8 * d + 2] = as;
    sv.u[8 * d + 3] = bs; sv.u[8 * d + 4] = bs; sv.u[8 * d + 5] = bs;
    sv.u[8 * d + 6] = cs2; sv.u[8 * d + 7] = cs2;
    tv.u[8 * d + 0] = at; tv.u[8 * d + 1] = bt; tv.u[8 * d + 2] = ct;
    tv.u[8 * d + 3] = at; tv.u[8 * d + 4] = bt; tv.u[8 * d + 5] = ct;
    tv.u[8 * d + 6] = at; tv.u[8 * d + 7] = bt;
  }
  const float sp = fmaf(co[0], co[0], fmaf(co[1], co[1], co[2] * co[2]));
  const float g = bf16rn(sp), q1 = sp - g;
  const float h = bf16rn(q1), q2 = q1 - h;
  const float ii = bf16rn(q2);
  sv.u[24] = b2u(g); sv.u[25] = b2u(h); sv.u[26] = b2u(ii);
  tv.u[24] = 0x3F80; tv.u[25] = 0x3F80; tv.u[26] = 0x3F80;  // bf16(1.0)
  sv.u[27] = 0x3F80; sv.u[28] = 0x3F80; sv.u[29] = 0x3F80;
  tv.u[27] = b2u(g); tv.u[28] = b2u(h); tv.u[29] = b2u(ii);
  sv.u[30] = 0; sv.u[31] = 0; tv.u[30] = 0; tv.u[31] = 0;
  uint4* sd = (uint4*)(sArr + (size_t)i * NSLOT);
  uint4* td = (uint4*)(tArr + (size_t)i * NSLOT);
#pragma unroll
  for (int k = 0; k < 4; ++k) { sd[k] = sv.v[k]; td[k] = tv.v[k]; }
  wmin[i] = 0x7F800000u;  // +inf bits: > any clamped finite float's bits
  if (i == 0) out[0] = 0.f;
}

// Block: 4 waves x 8 row-tiles = 512 rows, 4 chunks (1024 cols) of its col-split.
// LDS staging via global_load_lds w=16 with pre-permuted global source (m173): LDS slot
// s holds (jt=s>>6, qr=(s>>4)&3, pt=s&15) so ds_read_b128 at lane*16 is linear
// (conflict-free) and is exactly the B-fragment (col=lane&15, k-quarter=lane>>4).
__global__ __launch_bounds__(256, 4) void chamfer_mfma_kernel(
    const unsigned short* __restrict__ sArr, const unsigned short* __restrict__ tArr,
    unsigned int* __restrict__ wmin) {
  const int bx = blockIdx.x;
  const int dirb = bx & 7;         // bx%8 -> XCD-aligned: per-XCD L2 sees one dirb's t-set
  const int rblk = (bx >> 3) & (RBLK - 1);  // 0..15 (512 rows each)
  const int csp = bx >> 7;         // 0..7 (1024 cols each)
  const int dir = dirb >> 2, b = dirb & 3;
  const unsigned short* sb = sArr + (size_t)((dir ? SETPTS : 0) + b * NPTS) * NSLOT;
  const unsigned short* tb = tArr + (size_t)((dir ? 0 : SETPTS) + b * NPTS) * NSLOT;
  unsigned int* wm = wmin + (size_t)dirb * NPTS;

  const int t = threadIdx.x;
  const int lane = t & 63, wid = t >> 6;
  const int l15 = lane & 15, l4 = lane >> 4;

  __shared__ uint4 sbuf[2][CHUNK_BYTES / 16];  // 2 x 16 KB
  char* cs = (char*)sbuf;

  const int rowbase = rblk * ROWS_BLK + wid * (RT * 16);  // wave owns 128 rows = 8 tiles
  bf16x8 a[RT];
#pragma unroll
  for (int m = 0; m < RT; ++m)
    a[m] = *(const bf16x8*)(sb + (size_t)(rowbase + m * 16 + l15) * NSLOT + l4 * 8);

  const char* gsrc[4];
#pragma unroll
  for (int k = 0; k < 4; ++k) {
    const int s = k * 256 + t;
    const int jt = s >> 6, qr = (s >> 4) & 3, pt = s & 15;
    gsrc[k] = (const char*)(tb + (size_t)(csp * COLS_PER + jt * 16 + pt) * NSLOT + qr * 8);
  }

  f32x4 acc[RT];
#pragma unroll
  for (int m = 0; m < RT; ++m) acc[m] = (f32x4){INFINITY, INFINITY, INFINITY, INFINITY};
  const f32x4 zero = {0.f, 0.f, 0.f, 0.f};

#pragma unroll
  for (int k = 0; k < 4; ++k)
    __builtin_amdgcn_global_load_lds(
        (const __attribute__((address_space(1))) void*)gsrc[k],
        (__attribute__((address_space(3))) void*)(cs + (k * 256 + t) * 16), 16, 0, 0);
  __syncthreads();

  int cur = 0;
  for (int c = 0; c < CHUNKS_PER; ++c) {
    if (c + 1 < CHUNKS_PER) {  // prefetch next chunk into the other buffer
#pragma unroll
      for (int k = 0; k < 4; ++k)
        __builtin_amdgcn_global_load_lds(
            (const __attribute__((address_space(1))) void*)(gsrc[k] + (size_t)(c + 1) * CHUNK_BYTES),
            (__attribute__((address_space(3))) void*)(cs + (cur ^ 1) * CHUNK_BYTES + (k * 256 + t) * 16),
            16, 0, 0);
    }
    const char* bbase = cs + cur * CHUNK_BYTES + lane * 16;
#pragma unroll 2
    for (int jt = 0; jt < 16; jt += 2) {  // col-tile PAIRS: min3 folds two results/op
      const bf16x8 bfA = *(const bf16x8*)(bbase + jt * 1024);        // linear ds_read_b128
      const bf16x8 bfB = *(const bf16x8*)(bbase + (jt + 1) * 1024);
#pragma unroll
      for (int m = 0; m < RT; ++m) {
        const f32x4 dA = __builtin_amdgcn_mfma_f32_16x16x32_bf16(a[m], bfA, zero, 0, 0, 0);
        const f32x4 dB = __builtin_amdgcn_mfma_f32_16x16x32_bf16(a[m], bfB, zero, 0, 0, 0);
#pragma unroll
        for (int r = 0; r < 4; ++r)
          acc[m][r] = fminf(fminf(acc[m][r], dA[r]), dB[r]);  // v_min3_f32
      }
    }
    __syncthreads();  // implicit vmcnt(0): next buffer staged; cur safe to overwrite
    cur ^= 1;
  }

  // fold the 16 col-lanes (same lane>>4 group) -> this block's row-mins
#pragma unroll
  for (int mk = 1; mk <= 8; mk <<= 1) {
#pragma unroll
    for (int m = 0; m < RT; ++m)
#pragma unroll
      for (int r = 0; r < 4; ++r)
        acc[m][r] = fminf(acc[m][r], __shfl_xor(acc[m][r], mk, 64));
  }
  if (l15 == 0) {  // C/D: col=lane&15, row=(lane>>4)*4+r [m89]
#pragma unroll
    for (int m = 0; m < RT; ++m)
#pragma unroll
      for (int r = 0; r < 4; ++r)
        atomicMin(&wm[rowbase + m * 16 + l4 * 4 + r], __float_as_uint(fmaxf(acc[m][r], 0.f)));
  }
}

__global__ __launch_bounds__(256) void chamfer_reduce_kernel(const unsigned int* __restrict__ wmin,
                                                             float* __restrict__ out) {
  // 65536 elements; 64 blocks x 256 threads x 4 elems
  float s = 0.f;
  const int base = blockIdx.x * 1024 + threadIdx.x;
#pragma unroll
  for (int k = 0; k < 4; ++k) s += __uint_as_float(wmin[base + k * 256]);
#pragma unroll
  for (int off = 32; off > 0; off >>= 1) s += __shfl_down(s, off, 64);
  __shared__ float wsum[4];
  const int lane = threadIdx.x & 63, wid = threadIdx.x >> 6;
  if (lane == 0) wsum[wid] = s;
  __syncthreads();
  if (threadIdx.x == 0) atomicAdd(out, wsum[0] + wsum[1] + wsum[2] + wsum[3]);
}

extern "C" void kernel_launch(void* const* d_in, const int* in_sizes, int n_in,
                              void* d_out, int out_size, void* d_ws, size_t ws_size,
                              hipStream_t stream) {
  const float* p1 = (const float*)d_in[0];
  const float* p2 = (const float*)d_in[1];
  float* out = (float*)d_out;
  unsigned short* sArr = (unsigned short*)d_ws;                       // 4 MB
  unsigned short* tArr = (unsigned short*)((char*)d_ws + (4 << 20));  // 4 MB
  unsigned int* wmin = (unsigned int*)((char*)d_ws + (8 << 20));      // 256 KB

  chamfer_prep_kernel<<<dim3(TOTPTS / 256), dim3(256), 0, stream>>>(p1, p2, sArr, tArr, wmin, out);
  chamfer_mfma_kernel<<<dim3(8 * RBLK * CSPLIT), dim3(256), 0, stream>>>(sArr, tArr, wmin);
  chamfer_reduce_kernel<<<dim3(64), dim3(256), 0, stream>>>(wmin, out);
}

// Round 6
// 93.074 us; speedup vs baseline: 1.0602x; 1.0132x over previous
//
#include <hip/hip_runtime.h>

// Chamfer, B=4, N=M=8192 fp32 -> scalar. Round 9: 8 blocks/CU (32 waves/CU).
// Round-8 post-mortem: MFMA-density doubling was NEUTRAL -> DS/VALU-min not limiting.
// Round-5 counters prove clock is NOT throttled (MfmaUtil 26% is clock-invariant);
// pipes are idle because the kernel is latency/issue-bound at 4 waves/SIMD. The one
// proven lever: 2->4 waves/SIMD was -26%. So: double residency again.
//   RT=4 (a[4]+acc[4]+B pair ~55 VGPR <= 64 cap of __launch_bounds__(256,8)),
//   CHUNK_PTS=128 -> 2x8KB LDS = 16KB/block -> 8 blocks/CU = 128KB/CU,
//   CSPLIT=8 -> grid 2048 = 8 blocks/CU, full 32 waves/CU.
// Structure otherwise identical to round 6 (LDS dbuf, pre-permuted global_load_lds w=16,
// min3 pairs, clamped-uint atomicMin) -- identical arithmetic, absmax stays 0.

#define BATCH 4
#define NPTS 8192
#define SETPTS (BATCH * NPTS)       // 32768
#define TOTPTS (2 * SETPTS)         // 65536
#define NSLOT 32                    // bf16 K-slots per point (30 used)
#define CHUNK_PTS 128               // col points staged per chunk = 8 tiles
#define CSPLIT 8                    // col-splits per (dirb, rowblock)
#define COLS_PER (NPTS / CSPLIT)    // 1024 cols per block
#define CHUNKS_PER (COLS_PER / CHUNK_PTS)        // 8 chunks per block
#define CHUNK_BYTES (CHUNK_PTS * NSLOT * 2)      // 8192
#define RT 4                        // row-tiles per wave
#define ROWS_BLK (4 * RT * 16)      // 256 rows per block
#define RBLK (NPTS / ROWS_BLK)      // 32 row-blocks

typedef __attribute__((ext_vector_type(8))) short bf16x8;
typedef __attribute__((ext_vector_type(4))) float f32x4;

__device__ __forceinline__ float bf16rn(float v) {  // round-to-nearest-even to bf16 value
  unsigned u = __float_as_uint(v);
  u = (u + 0x7FFFu + ((u >> 16) & 1u)) & 0xFFFF0000u;
  return __uint_as_float(u);
}
__device__ __forceinline__ unsigned short b2u(float v) {  // bf16 bits of a bf16-valued f32
  return (unsigned short)(__float_as_uint(v) >> 16);
}

// Per point: s-vec (row role, carries the -2 factor) and t-vec (col role):
//   coord d: s[8d+]: [-2a,-2a,-2a,-2b,-2b,-2b,-2c,-2c]   t[8d+]: [d,e,f,d,e,f,d,e]
//     -> limb pairs ad,ae,af,bd,be,bf,cd,ce (drops only ~2^-36 c*f)
//   slots 24-26: s = split(|p|^2), t = 1 ; slots 27-29: s = 1, t = split(|q|^2); 30-31: 0.
__global__ __launch_bounds__(256) void chamfer_prep_kernel(
    const float* __restrict__ p1, const float* __restrict__ p2,
    unsigned short* __restrict__ sArr, unsigned short* __restrict__ tArr,
    unsigned int* __restrict__ wmin, float* __restrict__ out) {
  const int i = blockIdx.x * 256 + threadIdx.x;  // 0..65535
  const float* src = (i < SETPTS) ? (p1 + 3 * (size_t)i) : (p2 + 3 * (size_t)(i - SETPTS));
  const float co[3] = {src[0], src[1], src[2]};
  union { unsigned short u[32]; uint4 v[4]; } sv, tv;
#pragma unroll
  for (int d = 0; d < 3; ++d) {
    const float v = co[d];
    const float a = bf16rn(v), r1 = v - a;        // Sterbenz-exact residuals
    const float bb = bf16rn(r1), r2 = r1 - bb;
    const float cc = bf16rn(r2);
    const unsigned short as = b2u(-2.f * a), bs = b2u(-2.f * bb), cs2 = b2u(-2.f * cc);
    const unsigned short at = b2u(a), bt = b2u(bb), ct = b2u(cc);
    sv.u[8 * d + 0] = as; sv.u[8 * d + 1] = as; sv.u[8 * d + 2] = as;
    sv.u[8 * d + 3] = bs; sv.u[8 * d + 4] = bs; sv.u[8 * d + 5] = bs;
    sv.u[8 * d + 6] = cs2; sv.u[8 * d + 7] = cs2;
    tv.u[8 * d + 0] = at; tv.u[8 * d + 1] = bt; tv.u[8 * d + 2] = ct;
    tv.u[8 * d + 3] = at; tv.u[8 * d + 4] = bt; tv.u[8 * d + 5] = ct;
    tv.u[8 * d + 6] = at; tv.u[8 * d + 7] = bt;
  }
  const float sp = fmaf(co[0], co[0], fmaf(co[1], co[1], co[2] * co[2]));
  const float g = bf16rn(sp), q1 = sp - g;
  const float h = bf16rn(q1), q2 = q1 - h;
  const float ii = bf16rn(q2);
  sv.u[24] = b2u(g); sv.u[25] = b2u(h); sv.u[26] = b2u(ii);
  tv.u[24] = 0x3F80; tv.u[25] = 0x3F80; tv.u[26] = 0x3F80;  // bf16(1.0)
  sv.u[27] = 0x3F80; sv.u[28] = 0x3F80; sv.u[29] = 0x3F80;
  tv.u[27] = b2u(g); tv.u[28] = b2u(h); tv.u[29] = b2u(ii);
  sv.u[30] = 0; sv.u[31] = 0; tv.u[30] = 0; tv.u[31] = 0;
  uint4* sd = (uint4*)(sArr + (size_t)i * NSLOT);
  uint4* td = (uint4*)(tArr + (size_t)i * NSLOT);
#pragma unroll
  for (int k = 0; k < 4; ++k) { sd[k] = sv.v[k]; td[k] = tv.v[k]; }
  wmin[i] = 0x7F800000u;  // +inf bits: > any clamped finite float's bits
  if (i == 0) out[0] = 0.f;
}

// Block: 4 waves x 4 row-tiles = 256 rows, 8 chunks (1024 cols) of its col-split.
// LDS staging via global_load_lds w=16 with pre-permuted global source (m173): LDS slot
// s holds (jt=s>>6, qr=(s>>4)&3, pt=s&15) so ds_read_b128 at lane*16 is linear
// (conflict-free) and is exactly the B-fragment (col=lane&15, k-quarter=lane>>4).
__global__ __launch_bounds__(256, 8) void chamfer_mfma_kernel(
    const unsigned short* __restrict__ sArr, const unsigned short* __restrict__ tArr,
    unsigned int* __restrict__ wmin) {
  const int bx = blockIdx.x;
  const int dirb = bx & 7;         // bx%8 -> XCD-aligned: per-XCD L2 sees one dirb's t-set
  const int rblk = (bx >> 3) & (RBLK - 1);  // 0..31 (256 rows each)
  const int csp = bx >> 8;         // 0..7 (1024 cols each)
  const int dir = dirb >> 2, b = dirb & 3;
  const unsigned short* sb = sArr + (size_t)((dir ? SETPTS : 0) + b * NPTS) * NSLOT;
  const unsigned short* tb = tArr + (size_t)((dir ? 0 : SETPTS) + b * NPTS) * NSLOT;
  unsigned int* wm = wmin + (size_t)dirb * NPTS;

  const int t = threadIdx.x;
  const int lane = t & 63, wid = t >> 6;
  const int l15 = lane & 15, l4 = lane >> 4;

  __shared__ uint4 sbuf[2][CHUNK_BYTES / 16];  // 2 x 8 KB
  char* cs = (char*)sbuf;

  const int rowbase = rblk * ROWS_BLK + wid * (RT * 16);  // wave owns 64 rows = 4 tiles
  bf16x8 a[RT];
#pragma unroll
  for (int m = 0; m < RT; ++m)
    a[m] = *(const bf16x8*)(sb + (size_t)(rowbase + m * 16 + l15) * NSLOT + l4 * 8);

  const char* gsrc[2];
#pragma unroll
  for (int k = 0; k < 2; ++k) {
    const int s = k * 256 + t;  // 0..511 -> 8 col-tiles per chunk
    const int jt = s >> 6, qr = (s >> 4) & 3, pt = s & 15;
    gsrc[k] = (const char*)(tb + (size_t)(csp * COLS_PER + jt * 16 + pt) * NSLOT + qr * 8);
  }

  f32x4 acc[RT];
#pragma unroll
  for (int m = 0; m < RT; ++m) acc[m] = (f32x4){INFINITY, INFINITY, INFINITY, INFINITY};
  const f32x4 zero = {0.f, 0.f, 0.f, 0.f};

#pragma unroll
  for (int k = 0; k < 2; ++k)
    __builtin_amdgcn_global_load_lds(
        (const __attribute__((address_space(1))) void*)gsrc[k],
        (__attribute__((address_space(3))) void*)(cs + (k * 256 + t) * 16), 16, 0, 0);
  __syncthreads();

  int cur = 0;
  for (int c = 0; c < CHUNKS_PER; ++c) {
    if (c + 1 < CHUNKS_PER) {  // prefetch next chunk into the other buffer
#pragma unroll
      for (int k = 0; k < 2; ++k)
        __builtin_amdgcn_global_load_lds(
            (const __attribute__((address_space(1))) void*)(gsrc[k] + (size_t)(c + 1) * CHUNK_BYTES),
            (__attribute__((address_space(3))) void*)(cs + (cur ^ 1) * CHUNK_BYTES + (k * 256 + t) * 16),
            16, 0, 0);
    }
    const char* bbase = cs + cur * CHUNK_BYTES + lane * 16;
#pragma unroll
    for (int jt = 0; jt < 8; jt += 2) {  // col-tile PAIRS: min3 folds two results/op
      const bf16x8 bfA = *(const bf16x8*)(bbase + jt * 1024);        // linear ds_read_b128
      const bf16x8 bfB = *(const bf16x8*)(bbase + (jt + 1) * 1024);
#pragma unroll
      for (int m = 0; m < RT; ++m) {
        const f32x4 dA = __builtin_amdgcn_mfma_f32_16x16x32_bf16(a[m], bfA, zero, 0, 0, 0);
        const f32x4 dB = __builtin_amdgcn_mfma_f32_16x16x32_bf16(a[m], bfB, zero, 0, 0, 0);
#pragma unroll
        for (int r = 0; r < 4; ++r)
          acc[m][r] = fminf(fminf(acc[m][r], dA[r]), dB[r]);  // v_min3_f32
      }
    }
    __syncthreads();  // implicit vmcnt(0): next buffer staged; cur safe to overwrite
    cur ^= 1;
  }

  // fold the 16 col-lanes (same lane>>4 group) -> this block's row-mins
#pragma unroll
  for (int mk = 1; mk <= 8; mk <<= 1) {
#pragma unroll
    for (int m = 0; m < RT; ++m)
#pragma unroll
      for (int r = 0; r < 4; ++r)
        acc[m][r] = fminf(acc[m][r], __shfl_xor(acc[m][r], mk, 64));
  }
  if (l15 == 0) {  // C/D: col=lane&15, row=(lane>>4)*4+r [m89]
#pragma unroll
    for (int m = 0; m < RT; ++m)
#pragma unroll
      for (int r = 0; r < 4; ++r)
        atomicMin(&wm[rowbase + m * 16 + l4 * 4 + r], __float_as_uint(fmaxf(acc[m][r], 0.f)));
  }
}

__global__ __launch_bounds__(256) void chamfer_reduce_kernel(const unsigned int* __restrict__ wmin,
                                                             float* __restrict__ out) {
  // 65536 elements; 64 blocks x 256 threads x 4 elems
  float s = 0.f;
  const int base = blockIdx.x * 1024 + threadIdx.x;
#pragma unroll
  for (int k = 0; k < 4; ++k) s += __uint_as_float(wmin[base + k * 256]);
#pragma unroll
  for (int off = 32; off > 0; off >>= 1) s += __shfl_down(s, off, 64);
  __shared__ float wsum[4];
  const int lane = threadIdx.x & 63, wid = threadIdx.x >> 6;
  if (lane == 0) wsum[wid] = s;
  __syncthreads();
  if (threadIdx.x == 0) atomicAdd(out, wsum[0] + wsum[1] + wsum[2] + wsum[3]);
}

extern "C" void kernel_launch(void* const* d_in, const int* in_sizes, int n_in,
                              void* d_out, int out_size, void* d_ws, size_t ws_size,
                              hipStream_t stream) {
  const float* p1 = (const float*)d_in[0];
  const float* p2 = (const float*)d_in[1];
  float* out = (float*)d_out;
  unsigned short* sArr = (unsigned short*)d_ws;                       // 4 MB
  unsigned short* tArr = (unsigned short*)((char*)d_ws + (4 << 20));  // 4 MB
  unsigned int* wmin = (unsigned int*)((char*)d_ws + (8 << 20));      // 256 KB

  chamfer_prep_kernel<<<dim3(TOTPTS / 256), dim3(256), 0, stream>>>(p1, p2, sArr, tArr, wmin, out);
  chamfer_mfma_kernel<<<dim3(8 * RBLK * CSPLIT), dim3(256), 0, stream>>>(sArr, tArr, wmin);
  chamfer_reduce_kernel<<<dim3(64), dim3(256), 0, stream>>>(wmin, out);
}